// Round 2
// baseline (115.012 us; speedup 1.0000x reference)
//
#include <hip/hip_runtime.h>

// 4 rays per wave: 16 lanes/ray, 4 consecutive samples per lane (R7 base).
// R8: searchsorted replaced by analytic inverse scatter (kj = ceil(64*C-0.5),
//     atomicMax scatter + inclusive max-scan; wave_barrier fences phases).
// R9: (a) FUSED AFFINE SCAN — the transmittance product scan and the weight
//     sum scan were two dependent 4-step DPP chains separated by the weight
//     loop (weights need Pex). The recurrence S_L = S_{L-1} + Pex_L*t_L
//     (t_L = per-lane sum of alpha*pp) is scanned directly with the
//     associative combine (P,S)∘(P',S') = (P*P', S + P*S'): ONE 4-step DPP
//     chain. The +1e-5 per-weight offsets fold in analytically: cdf entry k
//     gets +k*1e-5 in the numerator, the total gets +63e-5.
//     (b) mark_s zero-init hoisted above the exp/sigmoid chain so its LDS
//     latency overlaps VALU work (same-wave DS ops execute in program order;
//     wave_barrier before the scatter fences compiler reordering).
// R10: resubmit of R9 — bench infra failed both prior rounds (no GPU), so
//     R9 has never been measured. No source change; do not stack unverified
//     edits on an unverified numerical transform.

template<int CTRL, int RM>
__device__ __forceinline__ float dpp_movf(float old, float x) {
    return __int_as_float(__builtin_amdgcn_update_dpp(
        __float_as_int(old), __float_as_int(x), CTRL, RM, 0xF, false));
}
template<int CTRL, int RM>
__device__ __forceinline__ int dpp_movi(int old, int x) {
    return __builtin_amdgcn_update_dpp(old, x, CTRL, RM, 0xF, false);
}
// row_shr:N = 0x110|N (row = 16 lanes), wave_shl:1 = 0x130 (validated R1-R8).
__device__ __forceinline__ float fast_rcp(float x) { return __builtin_amdgcn_rcpf(x); }
__device__ __forceinline__ float bperm(float x, int srclane) {
    return __int_as_float(__builtin_amdgcn_ds_bpermute(srclane << 2, __float_as_int(x)));
}

__global__ __launch_bounds__(256) void neus_upsample_kernel(
    const float* __restrict__ rays_o,
    const float* __restrict__ rays_d,
    const float* __restrict__ z_vals,
    const float* __restrict__ sdf,
    const int*   __restrict__ inv_s_ptr,
    float*       __restrict__ out,
    int n_rays)
{
    __shared__ float cdf_s[16][68];   // cdf per block-ray slot (stride-padded)
    __shared__ int   mark_s[16][64];  // scatter slots

    const int tid  = threadIdx.x;
    const int lane = tid & 63;
    const int L    = lane & 15;       // lane within ray
    const int slot = tid >> 4;        // block ray slot 0..15
    const int ray  = blockIdx.x * 16 + slot;
    if (ray >= n_rays) return;        // n_rays % 16 == 0; no __syncthreads used

    // R9b: init early — LDS store latency hides under the exp chain below.
    *(int4*)(&mark_s[slot][4 * L]) = make_int4(0, 0, 0, 0);

    const float inv_s = (float)inv_s_ptr[0];

    // ---- loads: 4 consecutive samples per lane ----
    const float4 zc = *(const float4*)(z_vals + ray * 64 + 4 * L);
    const float4 sc = *(const float4*)(sdf    + ray * 64 + 4 * L);
    const float ox = rays_o[ray*3+0], oy = rays_o[ray*3+1], oz = rays_o[ray*3+2];
    const float dx = rays_d[ray*3+0], dy = rays_d[ray*3+1], dz_ = rays_d[ray*3+2];
    const float a  = ox*ox + oy*oy + oz*oz;
    const float b2 = 2.0f * (ox*dx + oy*dy + oz*dz_);

    // sample 4L+4 from lane+1 (wave_shl:1; garbage at L==15 -> masked below)
    const float z4 = dpp_movf<0x130, 0xF>(zc.x, zc.x);
    const float s4 = dpp_movf<0x130, 0xF>(sc.x, sc.x);

    const float zv[5] = {zc.x, zc.y, zc.z, zc.w, z4};
    const float sv[5] = {sc.x, sc.y, sc.z, sc.w, s4};

    float r2[5];
    #pragma unroll
    for (int e = 0; e < 5; ++e) r2[e] = fmaf(zv[e], zv[e] + b2, a);

    float cr[4];
    #pragma unroll
    for (int e = 0; e < 4; ++e)
        cr[e] = (sv[e+1] - sv[e]) * fast_rcp(zv[e+1] - zv[e] + 1e-5f);

    // prev-interval cos: element 3 of lane-1 (row_shr:1; 0 at ray start)
    float prev = dpp_movf<0x111, 0xF>(0.0f, cr[3]);

    float alpha[4], pp[4];
    float prun = 1.0f;
    #pragma unroll
    for (int e = 0; e < 4; ++e) {
        float cosv = fminf(prev, cr[e]); prev = cr[e];
        cosv = fminf(fmaxf(cosv, -1000.0f), 0.0f);
        cosv = (fminf(r2[e], r2[e+1]) < 1.0f) ? cosv : 0.0f;
        const float mid = 0.5f * (sv[e] + sv[e+1]);
        const float hd  = 0.5f * (zv[e+1] - zv[e]);
        const float pe  = fmaf(-cosv, hd, mid);
        const float ne  = fmaf( cosv, hd, mid);
        const float pcf = fast_rcp(1.0f + __expf(-pe * inv_s));
        const float ncf = fast_rcp(1.0f + __expf(-ne * inv_s));
        alpha[e] = (pcf - ncf + 1e-5f) * fast_rcp(pcf + 1e-5f);
        pp[e] = prun;                      // in-lane exclusive transmittance
        prun *= (1.0f - alpha[e] + 1e-7f);
    }

    // ---- in-lane true-weight partials (no cross-lane dependency) ----
    // aw_e = alpha_e * pp_e; the +1e-5 offsets are handled analytically.
    float t_part[4];
    float tsum = 0.0f;
    #pragma unroll
    for (int e = 0; e < 4; ++e) {
        float awe = alpha[e] * pp[e];
        if (e == 3) awe = (L == 15) ? 0.0f : awe;   // interval 63 doesn't exist
        t_part[e] = tsum;
        tsum += awe;
    }

    // ---- R9a: single fused affine scan over the 16-lane row ----
    // (P,S)_L = inclusive combine of (prun_l, tsum_l), l = row_start..L, with
    // (P,S)∘(P',S') = (P*P', S + P*S'). Out-of-row source -> identity (1,0).
    float P = prun, S = tsum;
    {
        float Psh, Ssh;
        Psh = dpp_movf<0x111,0xF>(1.0f, P); Ssh = dpp_movf<0x111,0xF>(0.0f, S);
        S = fmaf(Psh, S, Ssh); P *= Psh;
        Psh = dpp_movf<0x112,0xF>(1.0f, P); Ssh = dpp_movf<0x112,0xF>(0.0f, S);
        S = fmaf(Psh, S, Ssh); P *= Psh;
        Psh = dpp_movf<0x114,0xF>(1.0f, P); Ssh = dpp_movf<0x114,0xF>(0.0f, S);
        S = fmaf(Psh, S, Ssh); P *= Psh;
        Psh = dpp_movf<0x118,0xF>(1.0f, P); Ssh = dpp_movf<0x118,0xF>(0.0f, S);
        S = fmaf(Psh, S, Ssh); P *= Psh;
    }
    const float Sex = dpp_movf<0x111, 0xF>(0.0f, S);  // sum over lanes < L
    const float Pex = dpp_movf<0x111, 0xF>(1.0f, P);  // transmittance into lane L

    const float T    = fmaf(63.0f, 1e-5f, bperm(S, lane | 15)); // + 63 offsets
    const float rtot = fast_rcp(T);
    const float z0   = bperm(zc.x, lane & 48);
    const float z63  = bperm(zc.w, lane | 15);
    const float h    = (z63 - z0) * (1.0f / 63.0f);

    // ---- cdf entries C[4L..4L+3]: (Sex + Pex*t_part[e] + (4L+e)*1e-5)/T ----
    const float kbase = (float)(4 * L);
    const float Sk    = fmaf(kbase, 1e-5f, Sex);
    float4 cvec;
    cvec.x = fmaf(Pex, t_part[0], Sk)           * rtot;   // == 0 at L==0
    cvec.y = (fmaf(Pex, t_part[1], Sk) + 1e-5f) * rtot;
    cvec.z = (fmaf(Pex, t_part[2], Sk) + 2e-5f) * rtot;
    cvec.w = (fmaf(Pex, t_part[3], Sk) + 3e-5f) * rtot;   // C[63] ~= 1 at L==15
    *(float4*)(&cdf_s[slot][4 * L]) = cvec;
    __builtin_amdgcn_wave_barrier();   // order: init+cdf before scatter

    // ---- scatter: entry j covers slots k >= ceil(64*C_j - 0.5) ----
    const float Cv[4] = {cvec.x, cvec.y, cvec.z, cvec.w};
    #pragma unroll
    for (int e = 0; e < 4; ++e) {
        const int kj = (int)ceilf(fmaf(64.0f, Cv[e], -0.5f));
        if (kj < 64) atomicMax(&mark_s[slot][kj], 4 * L + e);
    }
    __builtin_amdgcn_wave_barrier();   // order: scatter before gather

    // ---- inclusive max-scan over the 64 slots ----
    const int4 m4 = *(const int4*)(&mark_s[slot][4 * L]);
    const int i0 = m4.x;
    const int i1 = max(i0, m4.y);
    const int i2 = max(i1, m4.z);
    const int i3 = max(i2, m4.w);

    int ms = i3;
    ms = max(ms, dpp_movi<0x111, 0xF>(0, ms));
    ms = max(ms, dpp_movi<0x112, 0xF>(0, ms));
    ms = max(ms, dpp_movi<0x114, 0xF>(0, ms));
    ms = max(ms, dpp_movi<0x118, 0xF>(0, ms));
    const int Mex = dpp_movi<0x111, 0xF>(0, ms);   // max over lanes < L

    const int bl[4] = { min(max(Mex, i0), 62), min(max(Mex, i1), 62),
                        min(max(Mex, i2), 62), min(max(Mex, i3), 62) };

    // ---- interpolation: 2 LDS reads per query ----
    const float* cp = cdf_s[slot];
    float ov[4];
    #pragma unroll
    for (int e = 0; e < 4; ++e) {
        const float u  = fmaf(kbase + (float)e, 0.015625f, 0.0078125f);
        const int   b  = bl[e];
        const float cb = cp[b];
        const float ca = cp[b + 1];
        float gap = ca - cb;
        gap = (gap < 1e-5f) ? 1.0f : gap;
        const float t = (u - cb) * fast_rcp(gap);
        ov[e] = fmaf((float)b + t, h, z0);   // z0 + h*(below + t)
    }
    *(float4*)(out + ray * 64 + 4 * L) = make_float4(ov[0], ov[1], ov[2], ov[3]);
}

extern "C" void kernel_launch(void* const* d_in, const int* in_sizes, int n_in,
                              void* d_out, int out_size, void* d_ws, size_t ws_size,
                              hipStream_t stream) {
    const float* rays_o = (const float*)d_in[0];
    const float* rays_d = (const float*)d_in[1];
    const float* z_vals = (const float*)d_in[2];
    const float* sdf    = (const float*)d_in[3];
    // d_in[4] = n_importance (== 64, hardcoded)
    const int*   inv_s  = (const int*)d_in[5];
    float* out = (float*)d_out;

    const int n_rays = in_sizes[0] / 3;          // 131072
    const int blocks = (n_rays + 15) / 16;       // 16 rays per 256-thr block

    neus_upsample_kernel<<<blocks, 256, 0, stream>>>(
        rays_o, rays_d, z_vals, sdf, inv_s, out, n_rays);
}

// Round 6
// 114.477 us; speedup vs baseline: 1.0047x; 1.0047x over previous
//
#include <hip/hip_runtime.h>

// 4 rays per wave: 16 lanes/ray, 4 consecutive samples per lane (R7 base).
// R8: searchsorted -> analytic inverse scatter (kj = ceil(64*C-0.5),
//     atomicMax scatter + inclusive max-scan; wave_barrier fences phases).
// R9: fused affine scan (P,S)o(P',S') = (P*P', S+P*S') replaces product-scan
//     -> weight loop -> sum-scan; +1e-5 offsets folded analytically.
//     MEASURED NEUTRAL (115.01 vs 115.0) -> chain latency is hidden by wave
//     interleave; kernel is throughput/occupancy-bound, not chain-bound.
// R11: OCCUPANCY. rocprof: our kernel absent from top-5 (all 41-43us poison
//     fills) -> kernel <41us; ~31us for 99MB = 3.2 TB/s = 50% of achievable.
//     Theory: VGPR in the 65-128 band caps residency at 4 waves/SIMD (m69
//     steps at 64/128). Force <=64 via __launch_bounds__(256,4) + register
//     diet: alpha[]/pp[] folded into the sigmoid loop, r2[] -> 4 early
//     predicate floats (frees a,b2 before the exp chain), bl[] merged into
//     interp, z0/z63/h bperms hoisted next to the loads. Numerics identical.
// R12-R14: resubmits of R11 — GPU acquisition timed out each round; R11
//     never measured. Decision tree on next successful bench:
//     ~105us -> occupancy confirmed; ~115us -> pivot to LDS-phase/launch-gap;
//     >118us -> spills, revert bound keep diet.

template<int CTRL, int RM>
__device__ __forceinline__ float dpp_movf(float old, float x) {
    return __int_as_float(__builtin_amdgcn_update_dpp(
        __float_as_int(old), __float_as_int(x), CTRL, RM, 0xF, false));
}
template<int CTRL, int RM>
__device__ __forceinline__ int dpp_movi(int old, int x) {
    return __builtin_amdgcn_update_dpp(old, x, CTRL, RM, 0xF, false);
}
// row_shr:N = 0x110|N (row = 16 lanes), wave_shl:1 = 0x130 (validated R1-R10).
__device__ __forceinline__ float fast_rcp(float x) { return __builtin_amdgcn_rcpf(x); }
__device__ __forceinline__ float bperm(float x, int srclane) {
    return __int_as_float(__builtin_amdgcn_ds_bpermute(srclane << 2, __float_as_int(x)));
}

__global__ __launch_bounds__(256, 4) void neus_upsample_kernel(
    const float* __restrict__ rays_o,
    const float* __restrict__ rays_d,
    const float* __restrict__ z_vals,
    const float* __restrict__ sdf,
    const int*   __restrict__ inv_s_ptr,
    float*       __restrict__ out,
    int n_rays)
{
    __shared__ float cdf_s[16][68];   // cdf per block-ray slot (stride-padded)
    __shared__ int   mark_s[16][64];  // scatter slots

    const int tid  = threadIdx.x;
    const int lane = tid & 63;
    const int L    = lane & 15;       // lane within ray
    const int slot = tid >> 4;        // block ray slot 0..15
    const int ray  = blockIdx.x * 16 + slot;
    if (ray >= n_rays) return;        // n_rays % 16 == 0; no __syncthreads used

    // init early - LDS store latency hides under the exp chain below.
    *(int4*)(&mark_s[slot][4 * L]) = make_int4(0, 0, 0, 0);

    const float inv_s = (float)inv_s_ptr[0];

    // ---- loads: 4 consecutive samples per lane ----
    const float4 zc = *(const float4*)(z_vals + ray * 64 + 4 * L);
    const float4 sc = *(const float4*)(sdf    + ray * 64 + 4 * L);
    const float ox = rays_o[ray*3+0], oy = rays_o[ray*3+1], oz = rays_o[ray*3+2];
    const float dx = rays_d[ray*3+0], dy = rays_d[ray*3+1], dz_ = rays_d[ray*3+2];
    const float a  = ox*ox + oy*oy + oz*oz;
    const float b2 = 2.0f * (ox*dx + oy*dy + oz*dz_);

    // sample 4L+4 from lane+1 (wave_shl:1; garbage at L==15 -> masked below)
    const float z4 = dpp_movf<0x130, 0xF>(zc.x, zc.x);
    const float s4 = dpp_movf<0x130, 0xF>(sc.x, sc.x);

    // R11: hoisted - scan-independent; LDS-pipe latency overlaps exp chain.
    const float z0  = bperm(zc.x, lane & 48);
    const float z63 = bperm(zc.w, lane | 15);
    const float h   = (z63 - z0) * (1.0f / 63.0f);

    const float zv[5] = {zc.x, zc.y, zc.z, zc.w, z4};
    const float sv[5] = {sc.x, sc.y, sc.z, sc.w, s4};

    // ---- inside-sphere predicates early; frees a,b2 before the exp chain ----
    float insf[4];
    {
        float r2a = fmaf(zv[0], zv[0] + b2, a);
        #pragma unroll
        for (int e = 0; e < 4; ++e) {
            const float r2b = fmaf(zv[e+1], zv[e+1] + b2, a);
            insf[e] = (fminf(r2a, r2b) < 1.0f) ? 1.0f : 0.0f;
            r2a = r2b;
        }
    }

    float cr[4];
    #pragma unroll
    for (int e = 0; e < 4; ++e)
        cr[e] = (sv[e+1] - sv[e]) * fast_rcp(zv[e+1] - zv[e] + 1e-5f);

    // prev-interval cos: element 3 of lane-1 (row_shr:1; 0 at ray start)
    float prev = dpp_movf<0x111, 0xF>(0.0f, cr[3]);

    // ---- fused sigmoid/alpha/weight loop: only prun, tsum, t_part[] live ----
    float t_part[4];
    float tsum = 0.0f, prun = 1.0f;
    #pragma unroll
    for (int e = 0; e < 4; ++e) {
        float cosv = fminf(prev, cr[e]); prev = cr[e];
        cosv = fminf(fmaxf(cosv, -1000.0f), 0.0f) * insf[e];
        const float mid = 0.5f * (sv[e] + sv[e+1]);
        const float hd  = 0.5f * (zv[e+1] - zv[e]);
        const float pe  = fmaf(-cosv, hd, mid);
        const float ne  = fmaf( cosv, hd, mid);
        const float pcf = fast_rcp(1.0f + __expf(-pe * inv_s));
        const float ncf = fast_rcp(1.0f + __expf(-ne * inv_s));
        const float alpha = (pcf - ncf + 1e-5f) * fast_rcp(pcf + 1e-5f);
        float awe = alpha * prun;                 // alpha * exclusive-trans
        if (e == 3) awe = (L == 15) ? 0.0f : awe; // interval 63 doesn't exist
        t_part[e] = tsum;
        tsum += awe;
        prun *= (1.0f - alpha + 1e-7f);
    }

    // ---- fused affine scan over the 16-lane row (R9) ----
    // (P,S)_L = inclusive combine of (prun_l, tsum_l); identity (1,0).
    float P = prun, S = tsum;
    {
        float Psh, Ssh;
        Psh = dpp_movf<0x111,0xF>(1.0f, P); Ssh = dpp_movf<0x111,0xF>(0.0f, S);
        S = fmaf(Psh, S, Ssh); P *= Psh;
        Psh = dpp_movf<0x112,0xF>(1.0f, P); Ssh = dpp_movf<0x112,0xF>(0.0f, S);
        S = fmaf(Psh, S, Ssh); P *= Psh;
        Psh = dpp_movf<0x114,0xF>(1.0f, P); Ssh = dpp_movf<0x114,0xF>(0.0f, S);
        S = fmaf(Psh, S, Ssh); P *= Psh;
        Psh = dpp_movf<0x118,0xF>(1.0f, P); Ssh = dpp_movf<0x118,0xF>(0.0f, S);
        S = fmaf(Psh, S, Ssh); P *= Psh;
    }
    const float Sex = dpp_movf<0x111, 0xF>(0.0f, S);  // sum over lanes < L
    const float Pex = dpp_movf<0x111, 0xF>(1.0f, P);  // transmittance into lane L

    const float T    = fmaf(63.0f, 1e-5f, bperm(S, lane | 15)); // + 63 offsets
    const float rtot = fast_rcp(T);

    // ---- cdf entries C[4L..4L+3]: (Sex + Pex*t_part[e] + (4L+e)*1e-5)/T ----
    const float kbase = (float)(4 * L);
    const float Sk    = fmaf(kbase, 1e-5f, Sex);
    float4 cvec;
    cvec.x = fmaf(Pex, t_part[0], Sk)           * rtot;   // == 0 at L==0
    cvec.y = (fmaf(Pex, t_part[1], Sk) + 1e-5f) * rtot;
    cvec.z = (fmaf(Pex, t_part[2], Sk) + 2e-5f) * rtot;
    cvec.w = (fmaf(Pex, t_part[3], Sk) + 3e-5f) * rtot;   // C[63] ~= 1 at L==15
    *(float4*)(&cdf_s[slot][4 * L]) = cvec;
    __builtin_amdgcn_wave_barrier();   // order: init+cdf before scatter

    // ---- scatter: entry j covers slots k >= ceil(64*C_j - 0.5) ----
    const float Cv[4] = {cvec.x, cvec.y, cvec.z, cvec.w};
    #pragma unroll
    for (int e = 0; e < 4; ++e) {
        const int kj = (int)ceilf(fmaf(64.0f, Cv[e], -0.5f));
        if (kj < 64) atomicMax(&mark_s[slot][kj], 4 * L + e);
    }
    __builtin_amdgcn_wave_barrier();   // order: scatter before gather

    // ---- inclusive max-scan over the 64 slots ----
    const int4 m4 = *(const int4*)(&mark_s[slot][4 * L]);
    const int i0 = m4.x;
    const int i1 = max(i0, m4.y);
    const int i2 = max(i1, m4.z);
    const int i3 = max(i2, m4.w);

    int ms = i3;
    ms = max(ms, dpp_movi<0x111, 0xF>(0, ms));
    ms = max(ms, dpp_movi<0x112, 0xF>(0, ms));
    ms = max(ms, dpp_movi<0x114, 0xF>(0, ms));
    ms = max(ms, dpp_movi<0x118, 0xF>(0, ms));
    const int Mex = dpp_movi<0x111, 0xF>(0, ms);   // max over lanes < L

    // ---- bl + interpolation merged (R11): 2 LDS reads per query ----
    const float* cp = cdf_s[slot];
    const int iv[4] = {i0, i1, i2, i3};
    float ov[4];
    #pragma unroll
    for (int e = 0; e < 4; ++e) {
        const int   b  = min(max(Mex, iv[e]), 62);
        const float u  = fmaf(kbase + (float)e, 0.015625f, 0.0078125f);
        const float cb = cp[b];
        const float ca = cp[b + 1];
        float gap = ca - cb;
        gap = (gap < 1e-5f) ? 1.0f : gap;
        const float t = (u - cb) * fast_rcp(gap);
        ov[e] = fmaf((float)b + t, h, z0);   // z0 + h*(below + t)
    }
    *(float4*)(out + ray * 64 + 4 * L) = make_float4(ov[0], ov[1], ov[2], ov[3]);
}

extern "C" void kernel_launch(void* const* d_in, const int* in_sizes, int n_in,
                              void* d_out, int out_size, void* d_ws, size_t ws_size,
                              hipStream_t stream) {
    const float* rays_o = (const float*)d_in[0];
    const float* rays_d = (const float*)d_in[1];
    const float* z_vals = (const float*)d_in[2];
    const float* sdf    = (const float*)d_in[3];
    // d_in[4] = n_importance (== 64, hardcoded)
    const int*   inv_s  = (const int*)d_in[5];
    float* out = (float*)d_out;

    const int n_rays = in_sizes[0] / 3;          // 131072
    const int blocks = (n_rays + 15) / 16;       // 16 rays per 256-thr block

    neus_upsample_kernel<<<blocks, 256, 0, stream>>>(
        rays_o, rays_d, z_vals, sdf, inv_s, out, n_rays);
}